// Round 1
// baseline (551.136 us; speedup 1.0000x reference)
//
#include <hip/hip_runtime.h>

// GraphSAGE 2-layer, fp32. N=100000 nodes, E=1.6M edges, D: 64 -> 64 -> 32.
// Strategy: build CSR (by dst) on device each call, then
//   L1: agg = mean_{src in N(i)} x[src]  (wave/node, lane=dim)
//       h   = relu(agg@W1_l + b1 + x@W1_r)   (LDS-staged weights)
//   L2: t2 = h@W2_l ; out = h@W2_r + b2      (transform BEFORE aggregate: 32-dim gather)
//       out += mean_{src in N(i)} t2[src]

__global__ void k_count(const int* __restrict__ dst, int E, int* __restrict__ cnt) {
    int e = blockIdx.x * blockDim.x + threadIdx.x;
    if (e < E) atomicAdd(&cnt[dst[e]], 1);
}

// Phase A: per-block (1024-elem chunk) reduction of cnt
__global__ void k_scan_reduce(const int* __restrict__ cnt, int N, int* __restrict__ bsums) {
    __shared__ int s[256];
    int t = threadIdx.x;
    int base = blockIdx.x * 1024;
    int v = 0;
#pragma unroll
    for (int k = 0; k < 4; k++) {
        int i = base + t * 4 + k;
        if (i < N) v += cnt[i];
    }
    s[t] = v;
    __syncthreads();
    for (int off = 128; off > 0; off >>= 1) {
        if (t < off) s[t] += s[t + off];
        __syncthreads();
    }
    if (t == 0) bsums[blockIdx.x] = s[0];
}

// Phase B: serial exclusive scan of block sums (nb ~ 98, trivial)
__global__ void k_scan_bsums(int* __restrict__ bsums, int nb, int* __restrict__ row_off, int N) {
    if (threadIdx.x == 0) {
        int run = 0;
        for (int b = 0; b < nb; b++) { int v = bsums[b]; bsums[b] = run; run += v; }
        row_off[N] = run;  // == E
    }
}

// Phase C: per-block exclusive scan + block offset -> row_off, cursor copy
__global__ void k_scan_write(const int* __restrict__ cnt, int N, const int* __restrict__ bsums,
                             int* __restrict__ row_off, int* __restrict__ cursor) {
    __shared__ int s[256];
    int t = threadIdx.x;
    int base = blockIdx.x * 1024;
    int v[4];
#pragma unroll
    for (int k = 0; k < 4; k++) {
        int i = base + t * 4 + k;
        v[k] = (i < N) ? cnt[i] : 0;
    }
    int tsum = v[0] + v[1] + v[2] + v[3];
    s[t] = tsum;
    __syncthreads();
    for (int off = 1; off < 256; off <<= 1) {
        int add = (t >= off) ? s[t - off] : 0;
        __syncthreads();
        s[t] += add;
        __syncthreads();
    }
    int excl = s[t] - tsum + bsums[blockIdx.x];
#pragma unroll
    for (int k = 0; k < 4; k++) {
        int i = base + t * 4 + k;
        if (i < N) { row_off[i] = excl; cursor[i] = excl; excl += v[k]; }
    }
}

__global__ void k_fill(const int* __restrict__ src, const int* __restrict__ dst, int E,
                       int* __restrict__ cursor, int* __restrict__ col_src) {
    int e = blockIdx.x * blockDim.x + threadIdx.x;
    if (e < E) {
        int pos = atomicAdd(&cursor[dst[e]], 1);
        col_src[pos] = src[e];
    }
}

// one wave per node; lane = feature dim (64). mean of x[src] rows.
__global__ void k_agg_mean64(const float* __restrict__ x, const int* __restrict__ row_off,
                             const int* __restrict__ col_src, int N, float* __restrict__ agg) {
    int wid = (blockIdx.x * blockDim.x + threadIdx.x) >> 6;
    int lane = threadIdx.x & 63;
    if (wid >= N) return;
    int beg = row_off[wid], end = row_off[wid + 1];
    float s0 = 0.f, s1 = 0.f;
    int k = beg;
    for (; k + 1 < end; k += 2) {
        int a = col_src[k], b = col_src[k + 1];
        s0 += x[(size_t)a * 64 + lane];
        s1 += x[(size_t)b * 64 + lane];
    }
    if (k < end) s0 += x[(size_t)col_src[k] * 64 + lane];
    float deg = (float)(end - beg);
    float inv = deg > 0.f ? 1.f / deg : 0.f;
    agg[(size_t)wid * 64 + lane] = (s0 + s1) * inv;
}

// h = relu(agg@W1_l + b1 + x@W1_r). 4 rows/block, lane j = output dim.
__global__ __launch_bounds__(256) void k_lin1(const float* __restrict__ agg, const float* __restrict__ x,
                                              const float* __restrict__ Wl, const float* __restrict__ b1,
                                              const float* __restrict__ Wr, int N, float* __restrict__ h) {
    __shared__ float sWl[64 * 64];
    __shared__ float sWr[64 * 64];
    int t = threadIdx.x;
    for (int i = t; i < 4096; i += 256) { sWl[i] = Wl[i]; sWr[i] = Wr[i]; }
    __syncthreads();
    int row = blockIdx.x * 4 + (t >> 6);
    int j = t & 63;
    if (row >= N) return;
    const float* ar = agg + (size_t)row * 64;
    const float* xr = x + (size_t)row * 64;
    float acc = b1[j];
#pragma unroll 8
    for (int d = 0; d < 64; d++) {
        acc += ar[d] * sWl[d * 64 + j] + xr[d] * sWr[d * 64 + j];
    }
    h[(size_t)row * 64 + j] = acc > 0.f ? acc : 0.f;
}

// t2 = h@W2_l ; out = h@W2_r + b2. 8 rows/block, lane j = output dim (32).
__global__ __launch_bounds__(256) void k_lin2(const float* __restrict__ h,
                                              const float* __restrict__ Wl, const float* __restrict__ b2,
                                              const float* __restrict__ Wr, int N,
                                              float* __restrict__ t2, float* __restrict__ out) {
    __shared__ float sWl[64 * 32];
    __shared__ float sWr[64 * 32];
    int t = threadIdx.x;
    for (int i = t; i < 2048; i += 256) { sWl[i] = Wl[i]; sWr[i] = Wr[i]; }
    __syncthreads();
    int row = blockIdx.x * 8 + (t >> 5);
    int j = t & 31;
    if (row >= N) return;
    const float* hr = h + (size_t)row * 64;
    float accl = 0.f, accr = b2[j];
#pragma unroll 8
    for (int d = 0; d < 64; d++) {
        float hv = hr[d];
        accl += hv * sWl[d * 32 + j];
        accr += hv * sWr[d * 32 + j];
    }
    t2[(size_t)row * 32 + j] = accl;
    out[(size_t)row * 32 + j] = accr;
}

// wave per node; lanes 0-31 = dims of even neighbors, 32-63 = odd neighbors.
__global__ void k_agg_add32(const float* __restrict__ t2, const int* __restrict__ row_off,
                            const int* __restrict__ col_src, int N, float* __restrict__ out) {
    int wid = (blockIdx.x * blockDim.x + threadIdx.x) >> 6;
    int lane = threadIdx.x & 63;
    if (wid >= N) return;
    int beg = row_off[wid], end = row_off[wid + 1];
    int half = lane >> 5;
    int d = lane & 31;
    float s = 0.f;
    for (int k = beg + half; k < end; k += 2) {
        int a = col_src[k];
        s += t2[(size_t)a * 32 + d];
    }
    s += __shfl_xor(s, 32);
    if (half == 0) {
        float deg = (float)(end - beg);
        float inv = deg > 0.f ? 1.f / deg : 0.f;
        out[(size_t)wid * 32 + d] += s * inv;
    }
}

extern "C" void kernel_launch(void* const* d_in, const int* in_sizes, int n_in,
                              void* d_out, int out_size, void* d_ws, size_t ws_size,
                              hipStream_t stream) {
    const float* x   = (const float*)d_in[0];
    const int*   ei  = (const int*)d_in[1];
    const float* W1l = (const float*)d_in[2];
    const float* b1  = (const float*)d_in[3];
    const float* W1r = (const float*)d_in[4];
    const float* W2l = (const float*)d_in[5];
    const float* b2  = (const float*)d_in[6];
    const float* W2r = (const float*)d_in[7];
    float* out = (float*)d_out;

    int N = in_sizes[0] / 64;
    int E = in_sizes[1] / 2;
    const int* src = ei;
    const int* dst = ei + E;

    // workspace carve (256B aligned)
    char* ws = (char*)d_ws;
    size_t off = 0;
    auto alloc = [&](size_t bytes) { void* p = ws + off; off += (bytes + 255) & ~(size_t)255; return p; };
    int* cnt      = (int*)alloc((size_t)N * 4);
    int* row_off  = (int*)alloc((size_t)(N + 1) * 4);
    int* cursor   = (int*)alloc((size_t)N * 4);
    int* bsums    = (int*)alloc(4096);
    int* col_src  = (int*)alloc((size_t)E * 4);
    float* agg    = (float*)alloc((size_t)N * 64 * 4);  // later reused as t2 (N*32)
    float* h      = (float*)alloc((size_t)N * 64 * 4);

    hipMemsetAsync(cnt, 0, (size_t)N * 4, stream);

    int nb = (N + 1023) / 1024;
    k_count<<<(E + 255) / 256, 256, 0, stream>>>(dst, E, cnt);
    k_scan_reduce<<<nb, 256, 0, stream>>>(cnt, N, bsums);
    k_scan_bsums<<<1, 64, 0, stream>>>(bsums, nb, row_off, N);
    k_scan_write<<<nb, 256, 0, stream>>>(cnt, N, bsums, row_off, cursor);
    k_fill<<<(E + 255) / 256, 256, 0, stream>>>(src, dst, E, cursor, col_src);

    // layer 1
    k_agg_mean64<<<(N * 64 + 255) / 256, 256, 0, stream>>>(x, row_off, col_src, N, agg);
    k_lin1<<<(N + 3) / 4, 256, 0, stream>>>(agg, x, W1l, b1, W1r, N, h);

    // layer 2 (transform-first)
    float* t2 = agg;  // reuse
    k_lin2<<<(N + 7) / 8, 256, 0, stream>>>(h, W2l, b2, W2r, N, t2, out);
    k_agg_add32<<<(N * 64 + 255) / 256, 256, 0, stream>>>(t2, row_off, col_src, N, out);
}

// Round 2
// 371.184 us; speedup vs baseline: 1.4848x; 1.4848x over previous
//
#include <hip/hip_runtime.h>

// GraphSAGE 2-layer, fp32. N=100000, E=1.6M, D: 64 -> 64 -> 32.
// Transform-first on BOTH layers (aggregation is linear):
//   t1l = x@W1l, t1r = x@W1r          (one register-blocked GEMM pass)
//   h   = relu(mean_agg(t1l) + t1r + b1)   (fused in gather, h written in-place over t1r)
//   t2l = h@W2l, t2r = h@W2r + b2
//   out = mean_agg(t2l) + t2r

typedef __attribute__((ext_vector_type(4))) float f4;

// ---------------- CSR build ----------------
__global__ void k_count(const int* __restrict__ dst, int E, int* __restrict__ cnt) {
    int e = blockIdx.x * blockDim.x + threadIdx.x;
    if (e < E) atomicAdd(&cnt[dst[e]], 1);
}

__global__ void k_scan_reduce(const int* __restrict__ cnt, int N, int* __restrict__ bsums) {
    __shared__ int s[256];
    int t = threadIdx.x;
    int base = blockIdx.x * 1024;
    int v = 0;
#pragma unroll
    for (int k = 0; k < 4; k++) {
        int i = base + t * 4 + k;
        if (i < N) v += cnt[i];
    }
    s[t] = v;
    __syncthreads();
    for (int off = 128; off > 0; off >>= 1) {
        if (t < off) s[t] += s[t + off];
        __syncthreads();
    }
    if (t == 0) bsums[blockIdx.x] = s[0];
}

__global__ void k_scan_bsums(int* __restrict__ bsums, int nb, int* __restrict__ row_off, int N) {
    if (threadIdx.x == 0) {
        int run = 0;
        for (int b = 0; b < nb; b++) { int v = bsums[b]; bsums[b] = run; run += v; }
        row_off[N] = run;
    }
}

__global__ void k_scan_write(const int* __restrict__ cnt, int N, const int* __restrict__ bsums,
                             int* __restrict__ row_off, int* __restrict__ cursor) {
    __shared__ int s[256];
    int t = threadIdx.x;
    int base = blockIdx.x * 1024;
    int v[4];
#pragma unroll
    for (int k = 0; k < 4; k++) {
        int i = base + t * 4 + k;
        v[k] = (i < N) ? cnt[i] : 0;
    }
    int tsum = v[0] + v[1] + v[2] + v[3];
    s[t] = tsum;
    __syncthreads();
    for (int off = 1; off < 256; off <<= 1) {
        int add = (t >= off) ? s[t - off] : 0;
        __syncthreads();
        s[t] += add;
        __syncthreads();
    }
    int excl = s[t] - tsum + bsums[blockIdx.x];
#pragma unroll
    for (int k = 0; k < 4; k++) {
        int i = base + t * 4 + k;
        if (i < N) { row_off[i] = excl; cursor[i] = excl; excl += v[k]; }
    }
}

__global__ void k_fill(const int* __restrict__ src, const int* __restrict__ dst, int E,
                       int* __restrict__ cursor, int* __restrict__ col_src) {
    int e = blockIdx.x * blockDim.x + threadIdx.x;
    if (e < E) {
        int pos = atomicAdd(&cursor[dst[e]], 1);
        col_src[pos] = src[e];
    }
}

// ---------------- GEMM 1: t1l = x@Wl, t1r = x@Wr ----------------
// 64 rows x 128 cols per block of 256 threads; thread = 4 rows x (4+4) cols.
__global__ __launch_bounds__(256) void k_gemm1(const float* __restrict__ x,
                                               const float* __restrict__ Wl,
                                               const float* __restrict__ Wr, int N,
                                               float* __restrict__ t1l, float* __restrict__ t1r) {
    __shared__ float sA[64 * 68];   // [d][row], stride 68 (16B-aligned reads, low conflicts)
    __shared__ float sWl[64 * 64];  // [d][c]
    __shared__ float sWr[64 * 64];
    int t = threadIdx.x;
    int r0 = blockIdx.x * 64;
    for (int i = t; i < 1024; i += 256) {
        *(f4*)&sWl[i * 4] = *(const f4*)&Wl[i * 4];
        *(f4*)&sWr[i * 4] = *(const f4*)&Wr[i * 4];
    }
    {
        int row = t >> 4;
        int d0 = (t & 15) * 4;
#pragma unroll
        for (int kk = 0; kk < 4; kk++) {
            int r = row + kk * 16;
            f4 v = {0.f, 0.f, 0.f, 0.f};
            if (r0 + r < N) v = *(const f4*)&x[(size_t)(r0 + r) * 64 + d0];
            sA[(d0 + 0) * 68 + r] = v[0];
            sA[(d0 + 1) * 68 + r] = v[1];
            sA[(d0 + 2) * 68 + r] = v[2];
            sA[(d0 + 3) * 68 + r] = v[3];
        }
    }
    __syncthreads();
    int ty = t >> 4;   // 0..15 -> rows ty*4..+4
    int tx = t & 15;   // cols tx*4..+4 in BOTH Wl and Wr
    f4 accl[4] = {{0.f,0.f,0.f,0.f},{0.f,0.f,0.f,0.f},{0.f,0.f,0.f,0.f},{0.f,0.f,0.f,0.f}};
    f4 accr[4] = {{0.f,0.f,0.f,0.f},{0.f,0.f,0.f,0.f},{0.f,0.f,0.f,0.f},{0.f,0.f,0.f,0.f}};
#pragma unroll 4
    for (int d = 0; d < 64; d++) {
        f4 a  = *(const f4*)&sA[d * 68 + ty * 4];
        f4 wl = *(const f4*)&sWl[d * 64 + tx * 4];
        f4 wr = *(const f4*)&sWr[d * 64 + tx * 4];
#pragma unroll
        for (int r = 0; r < 4; r++) {
            accl[r] += a[r] * wl;
            accr[r] += a[r] * wr;
        }
    }
#pragma unroll
    for (int r = 0; r < 4; r++) {
        int rr = r0 + ty * 4 + r;
        if (rr < N) {
            *(f4*)&t1l[(size_t)rr * 64 + tx * 4] = accl[r];
            *(f4*)&t1r[(size_t)rr * 64 + tx * 4] = accr[r];
        }
    }
}

// ---------------- GEMM 2: t2l = h@W2l, t2r = h@W2r + b2 ----------------
// 64 rows x (32+32) cols per block; thread = 4 rows x 4 cols of one matrix.
__global__ __launch_bounds__(256) void k_gemm2(const float* __restrict__ h,
                                               const float* __restrict__ Wl,
                                               const float* __restrict__ Wr,
                                               const float* __restrict__ b2, int N,
                                               float* __restrict__ t2l, float* __restrict__ t2r) {
    __shared__ float sA[64 * 68];
    __shared__ float sWl[64 * 32];
    __shared__ float sWr[64 * 32];
    int t = threadIdx.x;
    int r0 = blockIdx.x * 64;
    for (int i = t; i < 512; i += 256) {
        *(f4*)&sWl[i * 4] = *(const f4*)&Wl[i * 4];
        *(f4*)&sWr[i * 4] = *(const f4*)&Wr[i * 4];
    }
    {
        int row = t >> 4;
        int d0 = (t & 15) * 4;
#pragma unroll
        for (int kk = 0; kk < 4; kk++) {
            int r = row + kk * 16;
            f4 v = {0.f, 0.f, 0.f, 0.f};
            if (r0 + r < N) v = *(const f4*)&h[(size_t)(r0 + r) * 64 + d0];
            sA[(d0 + 0) * 68 + r] = v[0];
            sA[(d0 + 1) * 68 + r] = v[1];
            sA[(d0 + 2) * 68 + r] = v[2];
            sA[(d0 + 3) * 68 + r] = v[3];
        }
    }
    __syncthreads();
    int ty = t >> 4;
    int tx = t & 15;
    int m  = tx >> 3;          // 0 = W2l matrix, 1 = W2r matrix
    int c0 = (tx & 7) * 4;
    const float* sW = m ? sWr : sWl;
    f4 acc[4] = {{0.f,0.f,0.f,0.f},{0.f,0.f,0.f,0.f},{0.f,0.f,0.f,0.f},{0.f,0.f,0.f,0.f}};
#pragma unroll 4
    for (int d = 0; d < 64; d++) {
        f4 a = *(const f4*)&sA[d * 68 + ty * 4];
        f4 w = *(const f4*)&sW[d * 32 + c0];
#pragma unroll
        for (int r = 0; r < 4; r++) acc[r] += a[r] * w;
    }
    f4 bias = {0.f, 0.f, 0.f, 0.f};
    if (m) bias = *(const f4*)&b2[c0];
    float* dstp = m ? t2r : t2l;
#pragma unroll
    for (int r = 0; r < 4; r++) {
        int rr = r0 + ty * 4 + r;
        if (rr < N) *(f4*)&dstp[(size_t)rr * 32 + c0] = acc[r] + bias;
    }
}

// ---------------- Layer-1 gather: h = relu(mean(t1l[nbrs]) + t1r + b1) ----------------
// wave/node; lane = (slot 0..3, dim4 0..15): 4 neighbors per iter, x2 unroll.
__global__ void k_agg1(const float* __restrict__ t1l, const int* __restrict__ row_off,
                       const int* __restrict__ col_src, const float* __restrict__ b1,
                       int N, float* __restrict__ h /* == t1r, in-place */) {
    int wid = (blockIdx.x * blockDim.x + threadIdx.x) >> 6;
    int lane = threadIdx.x & 63;
    if (wid >= N) return;
    int beg = row_off[wid], end = row_off[wid + 1];
    int slot = lane >> 4;
    int d4 = (lane & 15) * 4;
    f4 s0 = {0.f,0.f,0.f,0.f}, s1 = {0.f,0.f,0.f,0.f};
    int k = beg + slot;
    for (; k + 4 < end; k += 8) {
        int a = col_src[k], b = col_src[k + 4];
        s0 += *(const f4*)&t1l[(size_t)a * 64 + d4];
        s1 += *(const f4*)&t1l[(size_t)b * 64 + d4];
    }
    if (k < end) s0 += *(const f4*)&t1l[(size_t)col_src[k] * 64 + d4];
    s0 += s1;
#pragma unroll
    for (int j = 0; j < 4; j++) {
        float v = s0[j];
        v += __shfl_xor(v, 16);
        v += __shfl_xor(v, 32);
        s0[j] = v;
    }
    if (lane < 16) {
        float deg = (float)(end - beg);
        float inv = deg > 0.f ? 1.f / deg : 0.f;
        f4 rr = *(const f4*)&h[(size_t)wid * 64 + d4];   // t1r value
        f4 bb = *(const f4*)&b1[d4];
        f4 o;
#pragma unroll
        for (int j = 0; j < 4; j++) {
            float v = s0[j] * inv + rr[j] + bb[j];
            o[j] = v > 0.f ? v : 0.f;
        }
        *(f4*)&h[(size_t)wid * 64 + d4] = o;
    }
}

// ---------------- Layer-2 gather: out = mean(t2l[nbrs]) + t2r ----------------
// wave/node; lane = (slot 0..7, dim4 0..7): 8 neighbors per iter, x2 unroll.
__global__ void k_agg2(const float* __restrict__ t2l, const float* __restrict__ t2r,
                       const int* __restrict__ row_off, const int* __restrict__ col_src,
                       int N, float* __restrict__ out) {
    int wid = (blockIdx.x * blockDim.x + threadIdx.x) >> 6;
    int lane = threadIdx.x & 63;
    if (wid >= N) return;
    int beg = row_off[wid], end = row_off[wid + 1];
    int slot = lane >> 3;
    int d4 = (lane & 7) * 4;
    f4 s0 = {0.f,0.f,0.f,0.f}, s1 = {0.f,0.f,0.f,0.f};
    int k = beg + slot;
    for (; k + 8 < end; k += 16) {
        int a = col_src[k], b = col_src[k + 8];
        s0 += *(const f4*)&t2l[(size_t)a * 32 + d4];
        s1 += *(const f4*)&t2l[(size_t)b * 32 + d4];
    }
    if (k < end) s0 += *(const f4*)&t2l[(size_t)col_src[k] * 32 + d4];
    s0 += s1;
#pragma unroll
    for (int j = 0; j < 4; j++) {
        float v = s0[j];
        v += __shfl_xor(v, 8);
        v += __shfl_xor(v, 16);
        v += __shfl_xor(v, 32);
        s0[j] = v;
    }
    if (lane < 8) {
        float deg = (float)(end - beg);
        float inv = deg > 0.f ? 1.f / deg : 0.f;
        f4 rr = *(const f4*)&t2r[(size_t)wid * 32 + d4];
        *(f4*)&out[(size_t)wid * 32 + d4] = s0 * inv + rr;
    }
}

extern "C" void kernel_launch(void* const* d_in, const int* in_sizes, int n_in,
                              void* d_out, int out_size, void* d_ws, size_t ws_size,
                              hipStream_t stream) {
    const float* x   = (const float*)d_in[0];
    const int*   ei  = (const int*)d_in[1];
    const float* W1l = (const float*)d_in[2];
    const float* b1  = (const float*)d_in[3];
    const float* W1r = (const float*)d_in[4];
    const float* W2l = (const float*)d_in[5];
    const float* b2  = (const float*)d_in[6];
    const float* W2r = (const float*)d_in[7];
    float* out = (float*)d_out;

    int N = in_sizes[0] / 64;
    int E = in_sizes[1] / 2;
    const int* src = ei;
    const int* dst = ei + E;

    char* ws = (char*)d_ws;
    size_t off = 0;
    auto alloc = [&](size_t bytes) { void* p = ws + off; off += (bytes + 255) & ~(size_t)255; return p; };
    int* cnt     = (int*)alloc((size_t)N * 4);
    int* row_off = (int*)alloc((size_t)(N + 1) * 4);
    int* cursor  = (int*)alloc((size_t)N * 4);
    int* bsums   = (int*)alloc(4096);
    int* col_src = (int*)alloc((size_t)E * 4);
    float* bufA  = (float*)alloc((size_t)N * 64 * 4);  // t1l; then t2l|t2r
    float* bufB  = (float*)alloc((size_t)N * 64 * 4);  // t1r; h written in-place

    float* t1l = bufA;
    float* t1r = bufB;
    float* h   = bufB;
    float* t2l = bufA;
    float* t2r = bufA + (size_t)N * 32;

    hipMemsetAsync(cnt, 0, (size_t)N * 4, stream);
    int nb = (N + 1023) / 1024;
    k_count<<<(E + 255) / 256, 256, 0, stream>>>(dst, E, cnt);
    k_scan_reduce<<<nb, 256, 0, stream>>>(cnt, N, bsums);
    k_scan_bsums<<<1, 64, 0, stream>>>(bsums, nb, row_off, N);
    k_scan_write<<<nb, 256, 0, stream>>>(cnt, N, bsums, row_off, cursor);
    k_fill<<<(E + 255) / 256, 256, 0, stream>>>(src, dst, E, cursor, col_src);

    int gb = (N + 63) / 64;
    k_gemm1<<<gb, 256, 0, stream>>>(x, W1l, W1r, N, t1l, t1r);
    k_agg1<<<(N * 64 + 255) / 256, 256, 0, stream>>>(t1l, row_off, col_src, b1, N, h);
    k_gemm2<<<gb, 256, 0, stream>>>(h, W2l, W2r, b2, N, t2l, t2r);
    k_agg2<<<(N * 64 + 255) / 256, 256, 0, stream>>>(t2l, t2r, row_off, col_src, N, out);
}

// Round 3
// 335.575 us; speedup vs baseline: 1.6424x; 1.1061x over previous
//
#include <hip/hip_runtime.h>

// GraphSAGE 2-layer, fp32. N=100000, E=1.6M, D: 64 -> 64 -> 32.
// Transform-first on BOTH layers (aggregation is linear):
//   t1l = x@W1l, t1r = x@W1r          (one register-blocked GEMM pass)
//   h   = relu(mean_agg(t1l) + t1r + b1)   (fused in gather, h in-place over t1r)
//   t2l = h@W2l, t2r = h@W2r + b2
//   out = mean_agg(t2l) + t2r
// CSR fill is split into 4 dst-range passes so the scatter's active col_src
// region (1.6 MB) stays L2-resident and lines merge before HBM writeback
// (R2: single-pass fill caused 105 MB WRITE_SIZE for a 6.4 MB array).

typedef __attribute__((ext_vector_type(4))) float f4;

// ---------------- CSR build ----------------
__global__ void k_count(const int* __restrict__ dst, int E, int* __restrict__ cnt) {
    int e = blockIdx.x * blockDim.x + threadIdx.x;
    if (e < E) atomicAdd(&cnt[dst[e]], 1);
}

__global__ void k_scan_reduce(const int* __restrict__ cnt, int N, int* __restrict__ bsums) {
    __shared__ int s[256];
    int t = threadIdx.x;
    int base = blockIdx.x * 1024;
    int v = 0;
#pragma unroll
    for (int k = 0; k < 4; k++) {
        int i = base + t * 4 + k;
        if (i < N) v += cnt[i];
    }
    s[t] = v;
    __syncthreads();
    for (int off = 128; off > 0; off >>= 1) {
        if (t < off) s[t] += s[t + off];
        __syncthreads();
    }
    if (t == 0) bsums[blockIdx.x] = s[0];
}

__global__ void k_scan_bsums(int* __restrict__ bsums, int nb, int* __restrict__ row_off, int N) {
    if (threadIdx.x == 0) {
        int run = 0;
        for (int b = 0; b < nb; b++) { int v = bsums[b]; bsums[b] = run; run += v; }
        row_off[N] = run;
    }
}

__global__ void k_scan_write(const int* __restrict__ cnt, int N, const int* __restrict__ bsums,
                             int* __restrict__ row_off, int* __restrict__ cursor) {
    __shared__ int s[256];
    int t = threadIdx.x;
    int base = blockIdx.x * 1024;
    int v[4];
#pragma unroll
    for (int k = 0; k < 4; k++) {
        int i = base + t * 4 + k;
        v[k] = (i < N) ? cnt[i] : 0;
    }
    int tsum = v[0] + v[1] + v[2] + v[3];
    s[t] = tsum;
    __syncthreads();
    for (int off = 1; off < 256; off <<= 1) {
        int add = (t >= off) ? s[t - off] : 0;
        __syncthreads();
        s[t] += add;
        __syncthreads();
    }
    int excl = s[t] - tsum + bsums[blockIdx.x];
#pragma unroll
    for (int k = 0; k < 4; k++) {
        int i = base + t * 4 + k;
        if (i < N) { row_off[i] = excl; cursor[i] = excl; excl += v[k]; }
    }
}

// One dst-range pass: only edges with dst in [lo,hi) scatter this pass.
__global__ void k_fill_pass(const int* __restrict__ src, const int* __restrict__ dst, int E,
                            int lo, int hi,
                            int* __restrict__ cursor, int* __restrict__ col_src) {
    int e = blockIdx.x * blockDim.x + threadIdx.x;
    if (e >= E) return;
    int d = dst[e];
    if (d >= lo && d < hi) {
        int pos = atomicAdd(&cursor[d], 1);
        col_src[pos] = src[e];
    }
}

// ---------------- GEMM 1: t1l = x@Wl, t1r = x@Wr ----------------
// 64 rows x 128 cols per block of 256 threads; thread = 4 rows x (4+4) cols.
__global__ __launch_bounds__(256) void k_gemm1(const float* __restrict__ x,
                                               const float* __restrict__ Wl,
                                               const float* __restrict__ Wr, int N,
                                               float* __restrict__ t1l, float* __restrict__ t1r) {
    __shared__ float sA[64 * 68];   // [d][row], stride 68
    __shared__ float sWl[64 * 64];  // [d][c]
    __shared__ float sWr[64 * 64];
    int t = threadIdx.x;
    int r0 = blockIdx.x * 64;
    for (int i = t; i < 1024; i += 256) {
        *(f4*)&sWl[i * 4] = *(const f4*)&Wl[i * 4];
        *(f4*)&sWr[i * 4] = *(const f4*)&Wr[i * 4];
    }
    {
        int row = t >> 4;
        int d0 = (t & 15) * 4;
#pragma unroll
        for (int kk = 0; kk < 4; kk++) {
            int r = row + kk * 16;
            f4 v = {0.f, 0.f, 0.f, 0.f};
            if (r0 + r < N) v = *(const f4*)&x[(size_t)(r0 + r) * 64 + d0];
            sA[(d0 + 0) * 68 + r] = v[0];
            sA[(d0 + 1) * 68 + r] = v[1];
            sA[(d0 + 2) * 68 + r] = v[2];
            sA[(d0 + 3) * 68 + r] = v[3];
        }
    }
    __syncthreads();
    int ty = t >> 4;
    int tx = t & 15;
    f4 accl[4] = {{0.f,0.f,0.f,0.f},{0.f,0.f,0.f,0.f},{0.f,0.f,0.f,0.f},{0.f,0.f,0.f,0.f}};
    f4 accr[4] = {{0.f,0.f,0.f,0.f},{0.f,0.f,0.f,0.f},{0.f,0.f,0.f,0.f},{0.f,0.f,0.f,0.f}};
#pragma unroll 4
    for (int d = 0; d < 64; d++) {
        f4 a  = *(const f4*)&sA[d * 68 + ty * 4];
        f4 wl = *(const f4*)&sWl[d * 64 + tx * 4];
        f4 wr = *(const f4*)&sWr[d * 64 + tx * 4];
#pragma unroll
        for (int r = 0; r < 4; r++) {
            accl[r] += a[r] * wl;
            accr[r] += a[r] * wr;
        }
    }
#pragma unroll
    for (int r = 0; r < 4; r++) {
        int rr = r0 + ty * 4 + r;
        if (rr < N) {
            *(f4*)&t1l[(size_t)rr * 64 + tx * 4] = accl[r];
            *(f4*)&t1r[(size_t)rr * 64 + tx * 4] = accr[r];
        }
    }
}

// ---------------- GEMM 2: t2l = h@W2l, t2r = h@W2r + b2 ----------------
__global__ __launch_bounds__(256) void k_gemm2(const float* __restrict__ h,
                                               const float* __restrict__ Wl,
                                               const float* __restrict__ Wr,
                                               const float* __restrict__ b2, int N,
                                               float* __restrict__ t2l, float* __restrict__ t2r) {
    __shared__ float sA[64 * 68];
    __shared__ float sWl[64 * 32];
    __shared__ float sWr[64 * 32];
    int t = threadIdx.x;
    int r0 = blockIdx.x * 64;
    for (int i = t; i < 512; i += 256) {
        *(f4*)&sWl[i * 4] = *(const f4*)&Wl[i * 4];
        *(f4*)&sWr[i * 4] = *(const f4*)&Wr[i * 4];
    }
    {
        int row = t >> 4;
        int d0 = (t & 15) * 4;
#pragma unroll
        for (int kk = 0; kk < 4; kk++) {
            int r = row + kk * 16;
            f4 v = {0.f, 0.f, 0.f, 0.f};
            if (r0 + r < N) v = *(const f4*)&h[(size_t)(r0 + r) * 64 + d0];
            sA[(d0 + 0) * 68 + r] = v[0];
            sA[(d0 + 1) * 68 + r] = v[1];
            sA[(d0 + 2) * 68 + r] = v[2];
            sA[(d0 + 3) * 68 + r] = v[3];
        }
    }
    __syncthreads();
    int ty = t >> 4;
    int tx = t & 15;
    int m  = tx >> 3;
    int c0 = (tx & 7) * 4;
    const float* sW = m ? sWr : sWl;
    f4 acc[4] = {{0.f,0.f,0.f,0.f},{0.f,0.f,0.f,0.f},{0.f,0.f,0.f,0.f},{0.f,0.f,0.f,0.f}};
#pragma unroll 4
    for (int d = 0; d < 64; d++) {
        f4 a = *(const f4*)&sA[d * 68 + ty * 4];
        f4 w = *(const f4*)&sW[d * 32 + c0];
#pragma unroll
        for (int r = 0; r < 4; r++) acc[r] += a[r] * w;
    }
    f4 bias = {0.f, 0.f, 0.f, 0.f};
    if (m) bias = *(const f4*)&b2[c0];
    float* dstp = m ? t2r : t2l;
#pragma unroll
    for (int r = 0; r < 4; r++) {
        int rr = r0 + ty * 4 + r;
        if (rr < N) *(f4*)&dstp[(size_t)rr * 32 + c0] = acc[r] + bias;
    }
}

// ---------------- Layer-1 gather: h = relu(mean(t1l[nbrs]) + t1r + b1) ----------------
__global__ void k_agg1(const float* __restrict__ t1l, const int* __restrict__ row_off,
                       const int* __restrict__ col_src, const float* __restrict__ b1,
                       int N, float* __restrict__ h /* == t1r, in-place */) {
    int wid = (blockIdx.x * blockDim.x + threadIdx.x) >> 6;
    int lane = threadIdx.x & 63;
    if (wid >= N) return;
    int beg = row_off[wid], end = row_off[wid + 1];
    int slot = lane >> 4;
    int d4 = (lane & 15) * 4;
    f4 s0 = {0.f,0.f,0.f,0.f}, s1 = {0.f,0.f,0.f,0.f};
    int k = beg + slot;
    for (; k + 4 < end; k += 8) {
        int a = col_src[k], b = col_src[k + 4];
        s0 += *(const f4*)&t1l[(size_t)a * 64 + d4];
        s1 += *(const f4*)&t1l[(size_t)b * 64 + d4];
    }
    if (k < end) s0 += *(const f4*)&t1l[(size_t)col_src[k] * 64 + d4];
    s0 += s1;
#pragma unroll
    for (int j = 0; j < 4; j++) {
        float v = s0[j];
        v += __shfl_xor(v, 16);
        v += __shfl_xor(v, 32);
        s0[j] = v;
    }
    if (lane < 16) {
        float deg = (float)(end - beg);
        float inv = deg > 0.f ? 1.f / deg : 0.f;
        f4 rr = *(const f4*)&h[(size_t)wid * 64 + d4];   // t1r value
        f4 bb = *(const f4*)&b1[d4];
        f4 o;
#pragma unroll
        for (int j = 0; j < 4; j++) {
            float v = s0[j] * inv + rr[j] + bb[j];
            o[j] = v > 0.f ? v : 0.f;
        }
        *(f4*)&h[(size_t)wid * 64 + d4] = o;
    }
}

// ---------------- Layer-2 gather: out = mean(t2l[nbrs]) + t2r ----------------
__global__ void k_agg2(const float* __restrict__ t2l, const float* __restrict__ t2r,
                       const int* __restrict__ row_off, const int* __restrict__ col_src,
                       int N, float* __restrict__ out) {
    int wid = (blockIdx.x * blockDim.x + threadIdx.x) >> 6;
    int lane = threadIdx.x & 63;
    if (wid >= N) return;
    int beg = row_off[wid], end = row_off[wid + 1];
    int slot = lane >> 3;
    int d4 = (lane & 7) * 4;
    f4 s0 = {0.f,0.f,0.f,0.f}, s1 = {0.f,0.f,0.f,0.f};
    int k = beg + slot;
    for (; k + 8 < end; k += 16) {
        int a = col_src[k], b = col_src[k + 8];
        s0 += *(const f4*)&t2l[(size_t)a * 32 + d4];
        s1 += *(const f4*)&t2l[(size_t)b * 32 + d4];
    }
    if (k < end) s0 += *(const f4*)&t2l[(size_t)col_src[k] * 32 + d4];
    s0 += s1;
#pragma unroll
    for (int j = 0; j < 4; j++) {
        float v = s0[j];
        v += __shfl_xor(v, 8);
        v += __shfl_xor(v, 16);
        v += __shfl_xor(v, 32);
        s0[j] = v;
    }
    if (lane < 8) {
        float deg = (float)(end - beg);
        float inv = deg > 0.f ? 1.f / deg : 0.f;
        f4 rr = *(const f4*)&t2r[(size_t)wid * 32 + d4];
        *(f4*)&out[(size_t)wid * 32 + d4] = s0 * inv + rr;
    }
}

extern "C" void kernel_launch(void* const* d_in, const int* in_sizes, int n_in,
                              void* d_out, int out_size, void* d_ws, size_t ws_size,
                              hipStream_t stream) {
    const float* x   = (const float*)d_in[0];
    const int*   ei  = (const int*)d_in[1];
    const float* W1l = (const float*)d_in[2];
    const float* b1  = (const float*)d_in[3];
    const float* W1r = (const float*)d_in[4];
    const float* W2l = (const float*)d_in[5];
    const float* b2  = (const float*)d_in[6];
    const float* W2r = (const float*)d_in[7];
    float* out = (float*)d_out;

    int N = in_sizes[0] / 64;
    int E = in_sizes[1] / 2;
    const int* src = ei;
    const int* dst = ei + E;

    char* ws = (char*)d_ws;
    size_t off = 0;
    auto alloc = [&](size_t bytes) { void* p = ws + off; off += (bytes + 255) & ~(size_t)255; return p; };
    int* cnt     = (int*)alloc((size_t)N * 4);
    int* row_off = (int*)alloc((size_t)(N + 1) * 4);
    int* cursor  = (int*)alloc((size_t)N * 4);
    int* bsums   = (int*)alloc(4096);
    int* col_src = (int*)alloc((size_t)E * 4);
    float* bufA  = (float*)alloc((size_t)N * 64 * 4);  // t1l; then t2l|t2r
    float* bufB  = (float*)alloc((size_t)N * 64 * 4);  // t1r; h in-place

    float* t1l = bufA;
    float* t1r = bufB;
    float* h   = bufB;
    float* t2l = bufA;
    float* t2r = bufA + (size_t)N * 32;

    hipMemsetAsync(cnt, 0, (size_t)N * 4, stream);
    int nb = (N + 1023) / 1024;
    k_count<<<(E + 255) / 256, 256, 0, stream>>>(dst, E, cnt);
    k_scan_reduce<<<nb, 256, 0, stream>>>(cnt, N, bsums);
    k_scan_bsums<<<1, 64, 0, stream>>>(bsums, nb, row_off, N);
    k_scan_write<<<nb, 256, 0, stream>>>(cnt, N, bsums, row_off, cursor);

    // 4-pass dst-range fill: active col_src region ~1.6 MB/pass stays L2-resident.
    const int NPASS = 4;
    int step = (N + NPASS - 1) / NPASS;
    for (int p = 0; p < NPASS; p++) {
        int lo = p * step;
        int hi = lo + step < N ? lo + step : N;
        k_fill_pass<<<(E + 255) / 256, 256, 0, stream>>>(src, dst, E, lo, hi, cursor, col_src);
    }

    int gb = (N + 63) / 64;
    k_gemm1<<<gb, 256, 0, stream>>>(x, W1l, W1r, N, t1l, t1r);
    k_agg1<<<(N * 64 + 255) / 256, 256, 0, stream>>>(t1l, row_off, col_src, b1, N, h);
    k_gemm2<<<gb, 256, 0, stream>>>(h, W2l, W2r, b2, N, t2l, t2r);
    k_agg2<<<(N * 64 + 255) / 256, 256, 0, stream>>>(t2l, t2r, row_off, col_src, N, out);
}

// Round 4
// 225.068 us; speedup vs baseline: 2.4488x; 1.4910x over previous
//
#include <hip/hip_runtime.h>

// GraphSAGE 2-layer, fp32 in/out. N=100000, E=1.6M, D: 64 -> 64 -> 32.
// Transform-first on BOTH layers; gathered tensors (t1l,t2l) stored bf16
// (harness threshold is bf16-8ulp) to halve gather traffic.
// CSR build: two-level bucket sort with LDS pre-aggregation -> ~400K global
// atomics instead of 3.2M (R3: each fabric atomic costs a 32B transaction;
// k_count alone showed 49.9MB WRITE_SIZE for a 400KB array).

typedef __attribute__((ext_vector_type(4))) float f4;
typedef __attribute__((ext_vector_type(8))) unsigned short us8;
typedef __attribute__((ext_vector_type(4))) unsigned short us4;

#define BSHIFT 9
#define BSZ (1 << BSHIFT)   // 512 nodes per bucket
#define NBMAX 256           // max buckets (N <= 131072)

static __device__ inline unsigned short f2bf(float f) {
    union { float f; unsigned u; } v; v.f = f;
    unsigned u = v.u;
    u = (u + 0x7FFFu + ((u >> 16) & 1u)) >> 16;   // RNE
    return (unsigned short)u;
}
static __device__ inline float bf2f(unsigned short h) {
    union { unsigned u; float f; } v; v.u = ((unsigned)h) << 16; return v.f;
}

// ---------------- CSR build (bucketed) ----------------
__global__ __launch_bounds__(256) void k_bhist(const int* __restrict__ dst, int E, int chunk,
                                               int NB, int* __restrict__ bucket_cnt) {
    __shared__ int hist[NBMAX];
    int t = threadIdx.x;
    hist[t] = 0;
    __syncthreads();
    int lo = blockIdx.x * chunk, hi = min(lo + chunk, E);
    for (int e = lo + t; e < hi; e += 256) atomicAdd(&hist[dst[e] >> BSHIFT], 1);
    __syncthreads();
    if (t < NB) { int c = hist[t]; if (c) atomicAdd(&bucket_cnt[t], c); }
}

__global__ void k_bscan(const int* __restrict__ bucket_cnt, int NB, int E, int N,
                        int* __restrict__ bucket_base, int* __restrict__ bucket_cur,
                        int* __restrict__ row_off) {
    if (threadIdx.x == 0) {
        int run = 0;
        for (int b = 0; b < NB; b++) { bucket_base[b] = run; bucket_cur[b] = run; run += bucket_cnt[b]; }
        bucket_base[NB] = run;
        row_off[N] = E;
    }
}

__global__ __launch_bounds__(256) void k_bscatter(const int* __restrict__ src, const int* __restrict__ dst,
                                                  int E, int chunk, int NB,
                                                  int* __restrict__ bucket_cur,
                                                  unsigned int* __restrict__ bdata) {
    __shared__ int lcnt[NBMAX], lbase[NBMAX], lcur[NBMAX];
    int t = threadIdx.x;
    lcnt[t] = 0;
    __syncthreads();
    int lo = blockIdx.x * chunk, hi = min(lo + chunk, E);
    for (int e = lo + t; e < hi; e += 256) atomicAdd(&lcnt[dst[e] >> BSHIFT], 1);
    __syncthreads();
    if (t < NB) { int c = lcnt[t]; lcur[t] = 0; if (c) lbase[t] = atomicAdd(&bucket_cur[t], c); }
    __syncthreads();
    for (int e = lo + t; e < hi; e += 256) {
        int d = dst[e];
        int b = d >> BSHIFT;
        int pos = lbase[b] + atomicAdd(&lcur[b], 1);
        bdata[pos] = ((unsigned)(d & (BSZ - 1)) << 17) | (unsigned)src[e];  // src < 2^17
    }
}

// One block per bucket: fine histogram + scan in LDS -> row_off, col_src.
__global__ __launch_bounds__(256) void k_bucket_csr(const unsigned int* __restrict__ bdata,
                                                    const int* __restrict__ bucket_base,
                                                    int N, int* __restrict__ row_off,
                                                    int* __restrict__ col_src) {
    __shared__ int fh[BSZ];
    __shared__ int wtot[4];
    int t = threadIdx.x;
    int b = blockIdx.x;
    int ebase = bucket_base[b], eend = bucket_base[b + 1];
    fh[2 * t] = 0; fh[2 * t + 1] = 0;
    __syncthreads();
    for (int i = ebase + t; i < eend; i += 256) atomicAdd(&fh[bdata[i] >> 17], 1);
    __syncthreads();
    int a0 = fh[2 * t], a1 = fh[2 * t + 1];
    int psum = a0 + a1;
    int lane = t & 63, w = t >> 6;
    int v = psum;
    for (int off = 1; off < 64; off <<= 1) { int u = __shfl_up(v, off); if (lane >= off) v += u; }
    if (lane == 63) wtot[w] = v;
    __syncthreads();
    int wbase = 0;
    for (int i = 0; i < w; i++) wbase += wtot[i];
    int excl = wbase + v - psum;     // exclusive over element pairs
    int e0 = excl, e1 = excl + a0;
    int n0 = (b << BSHIFT) + 2 * t, n1 = n0 + 1;
    if (n0 < N) row_off[n0] = ebase + e0;
    if (n1 < N) row_off[n1] = ebase + e1;
    fh[2 * t] = e0; fh[2 * t + 1] = e1;
    __syncthreads();
    for (int i = ebase + t; i < eend; i += 256) {
        unsigned vv = bdata[i];
        int dl = vv >> 17;
        int pos = atomicAdd(&fh[dl], 1);
        col_src[ebase + pos] = (int)(vv & 0x1FFFFu);
    }
}

// ---------------- GEMM 1: t1l(bf16) = x@Wl, t1r(f32) = x@Wr ----------------
__global__ __launch_bounds__(256) void k_gemm1(const float* __restrict__ x,
                                               const float* __restrict__ Wl,
                                               const float* __restrict__ Wr, int N,
                                               unsigned short* __restrict__ t1l,
                                               float* __restrict__ t1r) {
    __shared__ float sA[64 * 68];
    __shared__ float sWl[64 * 64];
    __shared__ float sWr[64 * 64];
    int t = threadIdx.x;
    int r0 = blockIdx.x * 64;
    for (int i = t; i < 1024; i += 256) {
        *(f4*)&sWl[i * 4] = *(const f4*)&Wl[i * 4];
        *(f4*)&sWr[i * 4] = *(const f4*)&Wr[i * 4];
    }
    {
        int row = t >> 4;
        int d0 = (t & 15) * 4;
#pragma unroll
        for (int kk = 0; kk < 4; kk++) {
            int r = row + kk * 16;
            f4 v = {0.f, 0.f, 0.f, 0.f};
            if (r0 + r < N) v = *(const f4*)&x[(size_t)(r0 + r) * 64 + d0];
            sA[(d0 + 0) * 68 + r] = v[0];
            sA[(d0 + 1) * 68 + r] = v[1];
            sA[(d0 + 2) * 68 + r] = v[2];
            sA[(d0 + 3) * 68 + r] = v[3];
        }
    }
    __syncthreads();
    int ty = t >> 4;
    int tx = t & 15;
    f4 accl[4] = {{0.f,0.f,0.f,0.f},{0.f,0.f,0.f,0.f},{0.f,0.f,0.f,0.f},{0.f,0.f,0.f,0.f}};
    f4 accr[4] = {{0.f,0.f,0.f,0.f},{0.f,0.f,0.f,0.f},{0.f,0.f,0.f,0.f},{0.f,0.f,0.f,0.f}};
#pragma unroll 4
    for (int d = 0; d < 64; d++) {
        f4 a  = *(const f4*)&sA[d * 68 + ty * 4];
        f4 wl = *(const f4*)&sWl[d * 64 + tx * 4];
        f4 wr = *(const f4*)&sWr[d * 64 + tx * 4];
#pragma unroll
        for (int r = 0; r < 4; r++) {
            accl[r] += a[r] * wl;
            accr[r] += a[r] * wr;
        }
    }
#pragma unroll
    for (int r = 0; r < 4; r++) {
        int rr = r0 + ty * 4 + r;
        if (rr < N) {
            us4 lv;
#pragma unroll
            for (int j = 0; j < 4; j++) lv[j] = f2bf(accl[r][j]);
            *(us4*)&t1l[(size_t)rr * 64 + tx * 4] = lv;
            *(f4*)&t1r[(size_t)rr * 64 + tx * 4] = accr[r];
        }
    }
}

// ---------------- GEMM 2: t2l(bf16) = h@W2l, t2r(f32) = h@W2r + b2 ----------------
__global__ __launch_bounds__(256) void k_gemm2(const float* __restrict__ h,
                                               const float* __restrict__ Wl,
                                               const float* __restrict__ Wr,
                                               const float* __restrict__ b2, int N,
                                               unsigned short* __restrict__ t2l,
                                               float* __restrict__ t2r) {
    __shared__ float sA[64 * 68];
    __shared__ float sWl[64 * 32];
    __shared__ float sWr[64 * 32];
    int t = threadIdx.x;
    int r0 = blockIdx.x * 64;
    for (int i = t; i < 512; i += 256) {
        *(f4*)&sWl[i * 4] = *(const f4*)&Wl[i * 4];
        *(f4*)&sWr[i * 4] = *(const f4*)&Wr[i * 4];
    }
    {
        int row = t >> 4;
        int d0 = (t & 15) * 4;
#pragma unroll
        for (int kk = 0; kk < 4; kk++) {
            int r = row + kk * 16;
            f4 v = {0.f, 0.f, 0.f, 0.f};
            if (r0 + r < N) v = *(const f4*)&h[(size_t)(r0 + r) * 64 + d0];
            sA[(d0 + 0) * 68 + r] = v[0];
            sA[(d0 + 1) * 68 + r] = v[1];
            sA[(d0 + 2) * 68 + r] = v[2];
            sA[(d0 + 3) * 68 + r] = v[3];
        }
    }
    __syncthreads();
    int ty = t >> 4;
    int tx = t & 15;
    int m  = tx >> 3;
    int c0 = (tx & 7) * 4;
    const float* sW = m ? sWr : sWl;
    f4 acc[4] = {{0.f,0.f,0.f,0.f},{0.f,0.f,0.f,0.f},{0.f,0.f,0.f,0.f},{0.f,0.f,0.f,0.f}};
#pragma unroll 4
    for (int d = 0; d < 64; d++) {
        f4 a = *(const f4*)&sA[d * 68 + ty * 4];
        f4 w = *(const f4*)&sW[d * 32 + c0];
#pragma unroll
        for (int r = 0; r < 4; r++) acc[r] += a[r] * w;
    }
    if (m) {
        f4 bias = *(const f4*)&b2[c0];
#pragma unroll
        for (int r = 0; r < 4; r++) {
            int rr = r0 + ty * 4 + r;
            if (rr < N) *(f4*)&t2r[(size_t)rr * 32 + c0] = acc[r] + bias;
        }
    } else {
#pragma unroll
        for (int r = 0; r < 4; r++) {
            int rr = r0 + ty * 4 + r;
            if (rr < N) {
                us4 lv;
#pragma unroll
                for (int j = 0; j < 4; j++) lv[j] = f2bf(acc[r][j]);
                *(us4*)&t2l[(size_t)rr * 32 + c0] = lv;
            }
        }
    }
}

// ---------------- Layer-1 gather: h = relu(mean(t1l[nbrs]) + t1r + b1) ----------------
// wave/node; lane = (slot 0..7, dim8 0..7): 8 neighbors/iter, x2 unroll, bf16 rows.
__global__ void k_agg1(const unsigned short* __restrict__ t1l, const int* __restrict__ row_off,
                       const int* __restrict__ col_src, const float* __restrict__ b1,
                       int N, float* __restrict__ h /* == t1r, in-place */) {
    int wid = (blockIdx.x * blockDim.x + threadIdx.x) >> 6;
    int lane = threadIdx.x & 63;
    if (wid >= N) return;
    int beg = row_off[wid], end = row_off[wid + 1];
    int slot = lane >> 3;
    int d8 = (lane & 7) * 8;
    f4 sa = {0.f,0.f,0.f,0.f}, sb = {0.f,0.f,0.f,0.f};
    f4 ta = {0.f,0.f,0.f,0.f}, tb = {0.f,0.f,0.f,0.f};
    int k = beg + slot;
    for (; k + 8 < end; k += 16) {
        us8 va = *(const us8*)&t1l[(size_t)col_src[k] * 64 + d8];
        us8 vb = *(const us8*)&t1l[(size_t)col_src[k + 8] * 64 + d8];
#pragma unroll
        for (int j = 0; j < 4; j++) {
            sa[j] += bf2f(va[j]);     sb[j] += bf2f(va[j + 4]);
            ta[j] += bf2f(vb[j]);     tb[j] += bf2f(vb[j + 4]);
        }
    }
    if (k < end) {
        us8 va = *(const us8*)&t1l[(size_t)col_src[k] * 64 + d8];
#pragma unroll
        for (int j = 0; j < 4; j++) { sa[j] += bf2f(va[j]); sb[j] += bf2f(va[j + 4]); }
    }
    sa += ta; sb += tb;
#pragma unroll
    for (int j = 0; j < 4; j++) {
        float v = sa[j];
        v += __shfl_xor(v, 8); v += __shfl_xor(v, 16); v += __shfl_xor(v, 32);
        sa[j] = v;
        float u = sb[j];
        u += __shfl_xor(u, 8); u += __shfl_xor(u, 16); u += __shfl_xor(u, 32);
        sb[j] = u;
    }
    if (slot == 0) {
        float deg = (float)(end - beg);
        float inv = deg > 0.f ? 1.f / deg : 0.f;
        f4 r0 = *(const f4*)&h[(size_t)wid * 64 + d8];
        f4 r1 = *(const f4*)&h[(size_t)wid * 64 + d8 + 4];
        f4 b0 = *(const f4*)&b1[d8];
        f4 b1v = *(const f4*)&b1[d8 + 4];
        f4 o0, o1;
#pragma unroll
        for (int j = 0; j < 4; j++) {
            float v0 = sa[j] * inv + r0[j] + b0[j];
            float v1 = sb[j] * inv + r1[j] + b1v[j];
            o0[j] = v0 > 0.f ? v0 : 0.f;
            o1[j] = v1 > 0.f ? v1 : 0.f;
        }
        *(f4*)&h[(size_t)wid * 64 + d8] = o0;
        *(f4*)&h[(size_t)wid * 64 + d8 + 4] = o1;
    }
}

// ---------------- Layer-2 gather: out = mean(t2l[nbrs]) + t2r ----------------
// wave/node; lane = (slot 0..15, dim8 0..3): 16 neighbors/iter, x2 unroll, bf16 rows.
__global__ void k_agg2(const unsigned short* __restrict__ t2l, const float* __restrict__ t2r,
                       const int* __restrict__ row_off, const int* __restrict__ col_src,
                       int N, float* __restrict__ out) {
    int wid = (blockIdx.x * blockDim.x + threadIdx.x) >> 6;
    int lane = threadIdx.x & 63;
    if (wid >= N) return;
    int beg = row_off[wid], end = row_off[wid + 1];
    int slot = lane >> 2;
    int d8 = (lane & 3) * 8;
    f4 sa = {0.f,0.f,0.f,0.f}, sb = {0.f,0.f,0.f,0.f};
    f4 ta = {0.f,0.f,0.f,0.f}, tb = {0.f,0.f,0.f,0.f};
    int k = beg + slot;
    for (; k + 16 < end; k += 32) {
        us8 va = *(const us8*)&t2l[(size_t)col_src[k] * 32 + d8];
        us8 vb = *(const us8*)&t2l[(size_t)col_src[k + 16] * 32 + d8];
#pragma unroll
        for (int j = 0; j < 4; j++) {
            sa[j] += bf2f(va[j]);     sb[j] += bf2f(va[j + 4]);
            ta[j] += bf2f(vb[j]);     tb[j] += bf2f(vb[j + 4]);
        }
    }
    if (k < end) {
        us8 va = *(const us8*)&t2l[(size_t)col_src[k] * 32 + d8];
#pragma unroll
        for (int j = 0; j < 4; j++) { sa[j] += bf2f(va[j]); sb[j] += bf2f(va[j + 4]); }
    }
    sa += ta; sb += tb;
#pragma unroll
    for (int j = 0; j < 4; j++) {
        float v = sa[j];
        v += __shfl_xor(v, 4); v += __shfl_xor(v, 8); v += __shfl_xor(v, 16); v += __shfl_xor(v, 32);
        sa[j] = v;
        float u = sb[j];
        u += __shfl_xor(u, 4); u += __shfl_xor(u, 8); u += __shfl_xor(u, 16); u += __shfl_xor(u, 32);
        sb[j] = u;
    }
    if (slot == 0) {
        float deg = (float)(end - beg);
        float inv = deg > 0.f ? 1.f / deg : 0.f;
        f4 r0 = *(const f4*)&t2r[(size_t)wid * 32 + d8];
        f4 r1 = *(const f4*)&t2r[(size_t)wid * 32 + d8 + 4];
        *(f4*)&out[(size_t)wid * 32 + d8]     = sa * inv + r0;
        *(f4*)&out[(size_t)wid * 32 + d8 + 4] = sb * inv + r1;
    }
}

extern "C" void kernel_launch(void* const* d_in, const int* in_sizes, int n_in,
                              void* d_out, int out_size, void* d_ws, size_t ws_size,
                              hipStream_t stream) {
    const float* x   = (const float*)d_in[0];
    const int*   ei  = (const int*)d_in[1];
    const float* W1l = (const float*)d_in[2];
    const float* b1  = (const float*)d_in[3];
    const float* W1r = (const float*)d_in[4];
    const float* W2l = (const float*)d_in[5];
    const float* b2  = (const float*)d_in[6];
    const float* W2r = (const float*)d_in[7];
    float* out = (float*)d_out;

    int N = in_sizes[0] / 64;
    int E = in_sizes[1] / 2;
    const int* src = ei;
    const int* dst = ei + E;
    int NB = (N + BSZ - 1) >> BSHIFT;   // 196

    char* ws = (char*)d_ws;
    size_t off = 0;
    auto alloc = [&](size_t bytes) { void* p = ws + off; off += (bytes + 255) & ~(size_t)255; return p; };
    int* bucket_cnt  = (int*)alloc((size_t)NB * 4);
    int* bucket_base = (int*)alloc((size_t)(NB + 1) * 4);
    int* bucket_cur  = (int*)alloc((size_t)NB * 4);
    int* row_off     = (int*)alloc((size_t)(N + 1) * 4);
    int* col_src     = (int*)alloc((size_t)E * 4);
    unsigned int* bdata = (unsigned int*)alloc((size_t)E * 4);      // dead after CSR; reused as t2l
    unsigned short* t1l = (unsigned short*)alloc((size_t)N * 64 * 2); // dead after agg1; reused as t2r
    float* t1r          = (float*)alloc((size_t)N * 64 * 4);          // h in-place

    unsigned short* t2l = (unsigned short*)bdata;  // N*32*2 <= E*4
    float* t2r          = (float*)t1l;             // N*32*4 == N*64*2
    float* h = t1r;

    hipMemsetAsync(bucket_cnt, 0, (size_t)NB * 4, stream);
    const int NBLK = 1024;
    int chunk = (E + NBLK - 1) / NBLK;
    k_bhist<<<NBLK, 256, 0, stream>>>(dst, E, chunk, NB, bucket_cnt);
    k_bscan<<<1, 64, 0, stream>>>(bucket_cnt, NB, E, N, bucket_base, bucket_cur, row_off);
    k_bscatter<<<NBLK, 256, 0, stream>>>(src, dst, E, chunk, NB, bucket_cur, bdata);
    k_bucket_csr<<<NB, 256, 0, stream>>>(bdata, bucket_base, N, row_off, col_src);

    int gb = (N + 63) / 64;
    k_gemm1<<<gb, 256, 0, stream>>>(x, W1l, W1r, N, t1l, t1r);
    k_agg1<<<(N * 64 + 255) / 256, 256, 0, stream>>>(t1l, row_off, col_src, b1, N, h);
    k_gemm2<<<gb, 256, 0, stream>>>(h, W2l, W2r, b2, N, t2l, t2r);
    k_agg2<<<(N * 64 + 255) / 256, 256, 0, stream>>>(t2l, t2r, row_off, col_src, N, out);
}